// Round 8
// baseline (307.069 us; speedup 1.0000x reference)
//
#include <hip/hip_runtime.h>
#include <math.h>

// Problem constants (B, N, L, D) from the reference setup_inputs().
#define BSZ 64
#define NN  128
#define LL  64
#define DD  768
#define NEGV (-9e9f)

#define TQ (BSZ * NN * DD / 4)   // text float4 count  = 1572864
#define IQ (BSZ * LL * DD / 4)   // image float4 count =  786432

typedef _Float16 f16x8 __attribute__((ext_vector_type(8)));  // 8 f16 = 4 VGPRs
typedef __attribute__((ext_vector_type(4))) float f32x4;     // MFMA 16x16 accum

// ---------------------------------------------------------------------------
// Kernel 0: fp32 -> fp16 (RTN).
// ---------------------------------------------------------------------------
__global__ __launch_bounds__(256) void k_prep(
    const float4* __restrict__ t4, const float4* __restrict__ g4,
    ushort4* __restrict__ A, ushort4* __restrict__ B)
{
    int id = blockIdx.x * 256 + threadIdx.x;
    const float4* src; ushort4* dst; int idx;
    if (id < TQ) { src = t4; dst = A; idx = id; }
    else         { src = g4; dst = B; idx = id - TQ; }
    float4 x = src[idx];
    _Float16 h0 = (_Float16)x.x, h1 = (_Float16)x.y;
    _Float16 h2 = (_Float16)x.z, h3 = (_Float16)x.w;
    ushort4 o;
    o.x = __builtin_bit_cast(unsigned short, h0);
    o.y = __builtin_bit_cast(unsigned short, h1);
    o.z = __builtin_bit_cast(unsigned short, h2);
    o.w = __builtin_bit_cast(unsigned short, h3);
    dst[idx] = o;
}

// ---------------------------------------------------------------------------
// Kernel 1: barrier-free wave-private GEMM+softmax.
// Grid 512 = (64 j) x (8 i-groups); ig = bid&7 (XCD-pinned under mod-8
// round-robin -> per-XCD A working set 1.57 MB, L2-resident).
// Block: 512 threads = 8 waves; B_j (64 x 768 fp16 = 96 KB) staged once in
// LDS (k-tiled, XOR-swizzled); ONE __syncthreads; then each wave owns pair
// (i = ig*8+wave, j): two 64-row halves, 24 k-steps each, A-frags direct
// global->VGPR (reg dbuf), 16 MFMA/step.  Epilogue in registers/shuffles
// with online-softmax merge across halves.  No K-loop barriers.
// ---------------------------------------------------------------------------
__global__ __launch_bounds__(512, 2) void k_scores(
    const unsigned short* __restrict__ A, const unsigned short* __restrict__ B,
    const int* __restrict__ tmask, const int* __restrict__ imask,
    float* __restrict__ S, float* __restrict__ W)
{
    __shared__ __align__(16) char Bs[24 * 4096];   // 96 KB: 24 BK=32 chunks
    __shared__ float tmiS[8 * NN];                 // 4 KB: masks for 8 i's
    __shared__ float imjS[LL];                     // 256 B

    const int bid = blockIdx.x;
    const int j  = bid >> 3;     // 0..63
    const int ig = bid & 7;      // 0..7  (XCD pin)

    const int tid  = threadIdx.x;
    const int wave = tid >> 6;   // 0..7
    const int lane = tid & 63;
    const int quad = lane >> 4;
    const int l15  = lane & 15;

    // ---- stage B_j into k-tiled swizzled LDS (one time) ----
    // chunk c: slot (col, k8) at c*4096 + (col*4 + (k8 ^ ((col>>1)&3)))*16,
    // holding B[col][c*32 + k8*8 .. +8]  (16 B)
    {
        const unsigned short* pb = B + (size_t)j * LL * DD;
#pragma unroll
        for (int it = 0; it < 12; it++) {
            int idx = it * 512 + tid;          // 0..6143
            int c   = idx >> 8;
            int r   = idx & 255;
            int col = r >> 2, k8 = r & 3;
            float4 v = *(const float4*)(pb + (size_t)col * DD + c * 32 + k8 * 8);
            int slot = (col << 2) + (k8 ^ ((col >> 1) & 3));
            *(float4*)(Bs + c * 4096 + slot * 16) = v;
        }
        for (int it = tid; it < 8 * NN; it += 512) {
            int il = it >> 7, n = it & 127;
            tmiS[it] = tmask[(ig * 8 + il) * NN + n] ? 1.f : 0.f;
        }
        if (tid < LL) imjS[tid] = imask[j * LL + tid] ? 1.f : 0.f;
    }
    __syncthreads();   // the ONLY block-wide barrier

    const int i = ig * 8 + wave;
    const bool diag = (j == i);
    float* Wb = W + (size_t)i * LL * NN;

    float imc[4];
#pragma unroll
    for (int tc = 0; tc < 4; tc++) imc[tc] = imjS[tc * 16 + l15];

    float rowacc = 0.f;
    float Mc[4], Ec[4], Wc[4];

#pragma unroll
    for (int half = 0; half < 2; half++) {
        // row masks for this half
        float tmr[4][4];
#pragma unroll
        for (int tr = 0; tr < 4; tr++)
#pragma unroll
            for (int rr = 0; rr < 4; rr++)
                tmr[tr][rr] = tmiS[wave * NN + half * 64 + tr * 16 + quad * 4 + rr];

        const unsigned short* pA =
            A + ((size_t)(i * NN + half * 64) * DD);

        f32x4 acc[4][4];
        const f32x4 zf = {0.f, 0.f, 0.f, 0.f};
#pragma unroll
        for (int tr = 0; tr < 4; tr++)
#pragma unroll
            for (int tc = 0; tc < 4; tc++) acc[tr][tc] = zf;

        // ---- K loop: 24 steps of BK=32, reg-dbuf A prefetch, no barriers ----
        f16x8 afc[4], afn[4];
#pragma unroll
        for (int tr = 0; tr < 4; tr++)
            afc[tr] = *(const f16x8*)(pA + (size_t)(tr * 16 + l15) * DD + quad * 8);
#pragma unroll
        for (int c = 0; c < 24; c++) {
            if (c < 23) {
#pragma unroll
                for (int tr = 0; tr < 4; tr++)
                    afn[tr] = *(const f16x8*)(pA + (size_t)(tr * 16 + l15) * DD
                                              + (c + 1) * 32 + quad * 8);
            }
            f16x8 bf[4];
#pragma unroll
            for (int tc = 0; tc < 4; tc++) {
                int col = tc * 16 + l15;
                bf[tc] = *(const f16x8*)(Bs + c * 4096 +
                         ((col << 2) + (quad ^ ((col >> 1) & 3))) * 16);
            }
#pragma unroll
            for (int tr = 0; tr < 4; tr++)
#pragma unroll
                for (int tc = 0; tc < 4; tc++)
                    acc[tr][tc] = __builtin_amdgcn_mfma_f32_16x16x32_f16(
                        afc[tr], bf[tc], acc[tr][tc], 0, 0, 0);
            if (c < 23) {
#pragma unroll
                for (int tr = 0; tr < 4; tr++) afc[tr] = afn[tr];
            }
        }

        // ---- row pass: masked softmax over the 64 cols (this j) ----
        // C/D: row = quad*4+rr (tile tr), col = l15 (tile tc)
#pragma unroll
        for (int tr = 0; tr < 4; tr++) {
#pragma unroll
            for (int rr = 0; rr < 4; rr++) {
                int row = half * 64 + tr * 16 + quad * 4 + rr;
                float tm = tmr[tr][rr];
                float vmv[4];
                float m = -INFINITY;
#pragma unroll
                for (int tc = 0; tc < 4; tc++) {
                    float v = acc[tr][tc][rr];
                    float vm = (tm != 0.f && imc[tc] != 0.f && v != 0.f) ? v : NEGV;
                    vmv[tc] = vm;
                    m = fmaxf(m, vm);
                }
                m = fmaxf(m, __shfl_xor(m, 1));
                m = fmaxf(m, __shfl_xor(m, 2));
                m = fmaxf(m, __shfl_xor(m, 4));
                m = fmaxf(m, __shfl_xor(m, 8));
                float ss = 0.f, ws = 0.f;
#pragma unroll
                for (int tc = 0; tc < 4; tc++) {
                    float e = __expf(vmv[tc] - m);
                    ss += e;
                    ws += imc[tc] * e * vmv[tc];
                }
                ss += __shfl_xor(ss, 1); ss += __shfl_xor(ss, 2);
                ss += __shfl_xor(ss, 4); ss += __shfl_xor(ss, 8);
                ws += __shfl_xor(ws, 1); ws += __shfl_xor(ws, 2);
                ws += __shfl_xor(ws, 4); ws += __shfl_xor(ws, 8);
                if (l15 == 0) rowacc += tm * (ws / ss);
                if (diag) {
                    float inv = 1.f / ss;
#pragma unroll
                    for (int tc = 0; tc < 4; tc++)
                        Wb[(size_t)(tc * 16 + l15) * NN + row] =
                            __expf(vmv[tc] - m) * inv;
                }
            }
        }

        // ---- col stats for this half (over its 64 rows), online merge ----
#pragma unroll
        for (int tc = 0; tc < 4; tc++) {
            float ic = imc[tc];
            float cm = -INFINITY;
#pragma unroll
            for (int tr = 0; tr < 4; tr++)
#pragma unroll
                for (int rr = 0; rr < 4; rr++) {
                    float v = acc[tr][tc][rr];
                    float tm = tmr[tr][rr];
                    float vm = (tm != 0.f && ic != 0.f && v != 0.f) ? v : NEGV;
                    cm = fmaxf(cm, vm);
                }
            cm = fmaxf(cm, __shfl_xor(cm, 16));
            cm = fmaxf(cm, __shfl_xor(cm, 32));
            float es = 0.f, wsum = 0.f;
#pragma unroll
            for (int tr = 0; tr < 4; tr++)
#pragma unroll
                for (int rr = 0; rr < 4; rr++) {
                    float v = acc[tr][tc][rr];
                    float tm = tmr[tr][rr];
                    float vm = (tm != 0.f && ic != 0.f && v != 0.f) ? v : NEGV;
                    float e = __expf(vm - cm);
                    es += e;
                    wsum += tm * e * vm;
                }
            es += __shfl_xor(es, 16); es += __shfl_xor(es, 32);
            wsum += __shfl_xor(wsum, 16); wsum += __shfl_xor(wsum, 32);
            if (half == 0) { Mc[tc] = cm; Ec[tc] = es; Wc[tc] = wsum; }
            else {
                float mn = fmaxf(Mc[tc], cm);
                float a = __expf(Mc[tc] - mn), b = __expf(cm - mn);
                Ec[tc] = Ec[tc] * a + es * b;
                Wc[tc] = Wc[tc] * a + wsum * b;
                Mc[tc] = mn;
            }
        }
    }

    // ---- assemble S[i][j] ----
    float colsum = 0.f;
#pragma unroll
    for (int tc = 0; tc < 4; tc++)
        colsum += imc[tc] * (Wc[tc] / Ec[tc]);
    colsum += __shfl_xor(colsum, 1); colsum += __shfl_xor(colsum, 2);
    colsum += __shfl_xor(colsum, 4); colsum += __shfl_xor(colsum, 8);
    // rowacc: nonzero only at l15==0 (4 lanes); full-wave xor sum
    float rt = rowacc;
    rt += __shfl_xor(rt, 1);  rt += __shfl_xor(rt, 2);
    rt += __shfl_xor(rt, 4);  rt += __shfl_xor(rt, 8);
    rt += __shfl_xor(rt, 16); rt += __shfl_xor(rt, 32);
    if (lane == 0) S[i * BSZ + j] = (rt + colsum) * (1.f / 128.f);
}

// ---------------------------------------------------------------------------
// Kernel 2: text_emb_i2s[b,n,d] = sum_l W[b][l][n] * img[b][l][d]
// Grid (64 b, 3 d-chunks).  Full W[b] (32 KB) in LDS; img read once.
// Block (0,0) additionally computes the loss from S (fused k_loss).
// ---------------------------------------------------------------------------
__global__ __launch_bounds__(256) void k_i2s(
    const float* __restrict__ W, const float* __restrict__ img,
    const float* __restrict__ S, float* __restrict__ out)
{
    __shared__ float Ws[LL * NN];   // 32 KB, [l][n]
    __shared__ float Ss[BSZ * BSZ]; // 16 KB (loss staging, block (0,0) only)
    const int b = blockIdx.x, tid = threadIdx.x;
    const float* Wb = W + (size_t)b * LL * NN;
#pragma unroll
    for (int q = 0; q < 8; q++) {
        int o = (tid + q * 256) * 4;
        *(float4*)&Ws[o] = *(const float4*)&Wb[o];
    }
    const bool doloss = (blockIdx.x == 0 && blockIdx.y == 0);
    if (doloss) {
#pragma unroll
        for (int q = 0; q < 16; q++) Ss[tid + q * 256] = S[tid + q * 256];
    }
    __syncthreads();

    const int d = blockIdx.y * 256 + tid;
    const float* ib = img + (size_t)b * LL * DD + d;
    float* ob = out + 1 + (size_t)b * NN * DD + d;   // slot 0 = loss

    for (int ng = 0; ng < 8; ng++) {
        float acc[16];
#pragma unroll
        for (int q = 0; q < 16; q++) acc[q] = 0.f;
        for (int l = 0; l < LL; l++) {
            float g = ib[(size_t)l * DD];
            const float* wrow = &Ws[l * NN + ng * 16];
            float4 w0 = *(const float4*)(wrow);
            float4 w1 = *(const float4*)(wrow + 4);
            float4 w2 = *(const float4*)(wrow + 8);
            float4 w3 = *(const float4*)(wrow + 12);
            acc[0]  = fmaf(w0.x, g, acc[0]);  acc[1]  = fmaf(w0.y, g, acc[1]);
            acc[2]  = fmaf(w0.z, g, acc[2]);  acc[3]  = fmaf(w0.w, g, acc[3]);
            acc[4]  = fmaf(w1.x, g, acc[4]);  acc[5]  = fmaf(w1.y, g, acc[5]);
            acc[6]  = fmaf(w1.z, g, acc[6]);  acc[7]  = fmaf(w1.w, g, acc[7]);
            acc[8]  = fmaf(w2.x, g, acc[8]);  acc[9]  = fmaf(w2.y, g, acc[9]);
            acc[10] = fmaf(w2.z, g, acc[10]); acc[11] = fmaf(w2.w, g, acc[11]);
            acc[12] = fmaf(w3.x, g, acc[12]); acc[13] = fmaf(w3.y, g, acc[13]);
            acc[14] = fmaf(w3.z, g, acc[14]); acc[15] = fmaf(w3.w, g, acc[15]);
        }
#pragma unroll
        for (int q = 0; q < 16; q++)
            ob[(size_t)(ng * 16 + q) * DD] = acc[q];
    }

    if (doloss && tid < 64) {
        float diag = Ss[tid * BSZ + tid];
        float m1 = -INFINITY, m2 = -INFINITY;
        for (int jj = 0; jj < BSZ; jj++) {
            m1 = fmaxf(m1, Ss[tid * BSZ + jj]);
            m2 = fmaxf(m2, Ss[jj * BSZ + tid]);
        }
        float s1 = 0.f, s2 = 0.f;
        for (int jj = 0; jj < BSZ; jj++) {
            s1 += __expf(Ss[tid * BSZ + jj] - m1);
            s2 += __expf(Ss[jj * BSZ + tid] - m2);
        }
        float p = 2.f * diag - (m1 + logf(s1)) - (m2 + logf(s2));
#pragma unroll
        for (int off = 32; off; off >>= 1) p += __shfl_down(p, off);
        if (tid == 0) out[0] = -p / (float)BSZ;
    }
}

// ---------------------------------------------------------------------------
extern "C" void kernel_launch(void* const* d_in, const int* in_sizes, int n_in,
                              void* d_out, int out_size, void* d_ws, size_t ws_size,
                              hipStream_t stream)
{
    (void)in_sizes; (void)n_in; (void)out_size; (void)ws_size;
    const float* text = (const float*)d_in[0];   // [64,128,768] fp32
    const float* img  = (const float*)d_in[1];   // [64, 64,768] fp32
    const int*   tm   = (const int*)d_in[2];     // [64,128] int32
    const int*   im   = (const int*)d_in[3];     // [64, 64] int32
    float* out = (float*)d_out;                  // [1 + 64*128*768] fp32

    // workspace layout (bytes); total ~21 MB
    char* ws = (char*)d_ws;
    unsigned short* A = (unsigned short*)(ws);                   // 12.58 MB fp16
    unsigned short* B = (unsigned short*)(ws + 12582912);        //  6.29 MB fp16
    float* S = (float*)(ws + 18874368);                          // 16 KB
    float* W = (float*)(ws + 18890752);                          //  2 MB

    k_prep<<<(TQ + IQ) / 256, 256, 0, stream>>>(
        (const float4*)text, (const float4*)img, (ushort4*)A, (ushort4*)B);

    k_scores<<<512, 512, 0, stream>>>(A, B, tm, im, S, W);

    dim3 g2(BSZ, 3);
    k_i2s<<<g2, 256, 0, stream>>>(W, img, S, out);
}

// Round 9
// 201.126 us; speedup vs baseline: 1.5267x; 1.5267x over previous
//
#include <hip/hip_runtime.h>
#include <math.h>

// Problem constants (B, N, L, D) from the reference setup_inputs().
#define BSZ 64
#define NN  128
#define LL  64
#define DD  768
#define NEGV (-9e9f)

#define TQ (BSZ * NN * DD / 4)   // text float4 count  = 1572864
#define IQ (BSZ * LL * DD / 4)   // image float4 count =  786432

typedef _Float16 f16x8 __attribute__((ext_vector_type(8)));  // 8 f16 = 4 VGPRs
typedef __attribute__((ext_vector_type(4))) float f32x4;     // MFMA 16x16 accum

// async 16B global -> LDS; dst is wave-uniform base, HW scatters +lane*16
__device__ __forceinline__ void gl_lds16(const void* g, void* l) {
    __builtin_amdgcn_global_load_lds(
        (const __attribute__((address_space(1))) void*)g,
        (__attribute__((address_space(3))) void*)l, 16, 0, 0);
}

// ---------------------------------------------------------------------------
// Kernel 0: fp32 -> fp16 (RTN).
// ---------------------------------------------------------------------------
__global__ __launch_bounds__(256) void k_prep(
    const float4* __restrict__ t4, const float4* __restrict__ g4,
    ushort4* __restrict__ A, ushort4* __restrict__ B)
{
    int id = blockIdx.x * 256 + threadIdx.x;
    const float4* src; ushort4* dst; int idx;
    if (id < TQ) { src = t4; dst = A; idx = id; }
    else         { src = g4; dst = B; idx = id - TQ; }
    float4 x = src[idx];
    _Float16 h0 = (_Float16)x.x, h1 = (_Float16)x.y;
    _Float16 h2 = (_Float16)x.z, h3 = (_Float16)x.w;
    ushort4 o;
    o.x = __builtin_bit_cast(unsigned short, h0);
    o.y = __builtin_bit_cast(unsigned short, h1);
    o.z = __builtin_bit_cast(unsigned short, h2);
    o.w = __builtin_bit_cast(unsigned short, h3);
    dst[idx] = o;
}

// ---------------------------------------------------------------------------
// Stage one BK=32 chunk: A 128 rows x 32 k (8 KB) + B 128 rows x 32 k (8 KB).
// LDS slot (row, k8s) at byte (row*4 + k8s)*16 holding global k8 =
// k8s ^ ((row>>1)&3).  Dst base is wave-uniform; HW adds lane*16.
// ---------------------------------------------------------------------------
__device__ __forceinline__ void stage_chunk(
    const unsigned short* __restrict__ pa, const unsigned short* __restrict__ pb,
    int k0, char* buf, int wave, int lane)
{
    int k8s = lane & 3;
#pragma unroll
    for (int c = 0; c < 2; c++) {
        int r  = c * 64 + wave * 16 + (lane >> 2);
        int k8 = k8s ^ ((r >> 1) & 3);
        gl_lds16(pa + (size_t)r * DD + k0 + k8 * 8, buf + c * 4096 + wave * 1024);
        gl_lds16(pb + (size_t)r * DD + k0 + k8 * 8, buf + 8192 + c * 4096 + wave * 1024);
    }
}

// ---------------------------------------------------------------------------
// Kernel 1: one block per (i, jp); tile 128 x 128 (2 j's); 4 waves, wave
// tile 64x64.  K-loop: 24 chunks of BK=32, 2 buffers, COMPUTE-FIRST order:
//   compute(c); __syncthreads(); stage(c+2) into the buffer just computed.
// The barrier's vmcnt(0) drain thus waits on loads issued a full iteration
// earlier (not the just-issued prefetch), and 4 blocks/CU (38.9 KB LDS)
// cover the residual stall.  Epilogue in registers/shuffles (verified R7).
// ---------------------------------------------------------------------------
__global__ __launch_bounds__(256, 4) void k_scores(
    const unsigned short* __restrict__ A, const unsigned short* __restrict__ B,
    const int* __restrict__ tmask, const int* __restrict__ imask,
    float* __restrict__ S, float* __restrict__ W)
{
    __shared__ __align__(16) char stage[2][16384];   // [buf][A 8K | B 8K]
    __shared__ float tmi[NN];          // 128 row masks
    __shared__ float imj[NN];          // 128 col masks (2 j's)
    __shared__ float rowredL[NN][2];   // per-row masked row-score, per local j
    __shared__ float cpmax[2][NN];     // per-wr col-max partials
    __shared__ float cpes[2][NN];      // per-wr col exp-sum partials
    __shared__ float cpws[2][NN];      // per-wr col weighted-sum partials

    // 4x4 block-group swizzle over 64 i x 32 jp
    const int bid = blockIdx.x;
    const int grp = bid >> 4, idx = bid & 15;
    const int gi = grp >> 3, gj = grp & 7;
    const int i  = gi * 4 + (idx >> 2);   // 0..63
    const int jp = gj * 4 + (idx & 3);    // 0..31
    const int j0 = jp * 2;

    const int tid  = threadIdx.x;
    const int wave = tid >> 6;
    const int lane = tid & 63;
    const int quad = lane >> 4;
    const int l15  = lane & 15;
    const int wr   = wave & 1;     // row half (64 rows)
    const int wc   = wave >> 1;    // local j (64 cols)

    if (tid < NN) {
        tmi[tid] = tmask[i * NN + tid] ? 1.f : 0.f;
        imj[tid] = imask[j0 * LL + tid] ? 1.f : 0.f;   // two j's contiguous
    }

    const unsigned short* pa = A + (size_t)i * NN * DD;
    const unsigned short* pb = B + (size_t)j0 * LL * DD;

    f32x4 acc[4][4];
    const f32x4 zf = {0.f, 0.f, 0.f, 0.f};
#pragma unroll
    for (int tr = 0; tr < 4; tr++)
#pragma unroll
        for (int tc = 0; tc < 4; tc++) acc[tr][tc] = zf;

    stage_chunk(pa, pb, 0,  stage[0], wave, lane);
    stage_chunk(pa, pb, 32, stage[1], wave, lane);
    __syncthreads();   // drains both startup stages

    for (int c = 0; c < 24; c++) {
        const char* Ab = stage[c & 1];
        const char* Bb = Ab + 8192;
        f16x8 af[4], bfr[4];
#pragma unroll
        for (int t = 0; t < 4; t++) {
            int row = wr * 64 + t * 16 + l15;
            af[t]  = *(const f16x8*)(Ab + ((row << 2) + (quad ^ ((row >> 1) & 3))) * 16);
            int col = wc * 64 + t * 16 + l15;
            bfr[t] = *(const f16x8*)(Bb + ((col << 2) + (quad ^ ((col >> 1) & 3))) * 16);
        }
#pragma unroll
        for (int tr = 0; tr < 4; tr++)
#pragma unroll
            for (int tc = 0; tc < 4; tc++)
                acc[tr][tc] = __builtin_amdgcn_mfma_f32_16x16x32_f16(
                    af[tr], bfr[tc], acc[tr][tc], 0, 0, 0);
        __syncthreads();   // drains stage(c+1) issued last iteration
        if (c + 2 < 24)
            stage_chunk(pa, pb, (c + 2) << 5, stage[c & 1], wave, lane);
    }

    // per-lane masks.  C/D layout per 16x16 tile: row = quad*4+rr, col = l15.
    float tmr[4][4];  // rows: wr*64 + tr*16 + quad*4 + rr
    float imc[4];     // cols: wc*64 + tc*16 + l15
#pragma unroll
    for (int tr = 0; tr < 4; tr++)
#pragma unroll
        for (int rr = 0; rr < 4; rr++)
            tmr[tr][rr] = tmi[wr * 64 + tr * 16 + quad * 4 + rr];
#pragma unroll
    for (int tc = 0; tc < 4; tc++)
        imc[tc] = imj[wc * 64 + tc * 16 + l15];

    // diagonal: block (i, jp) holds j==i iff jp == i>>1; owning wave wc == i&1
    const bool wdiag = (jp == (i >> 1)) && (wc == (i & 1));

    // ---- row pass: masked softmax over this wave's 64 cols (one j) ----
#pragma unroll
    for (int tr = 0; tr < 4; tr++) {
#pragma unroll
        for (int rr = 0; rr < 4; rr++) {
            int row = wr * 64 + tr * 16 + quad * 4 + rr;
            float tm = tmr[tr][rr];
            float vmv[4];
            float m = -INFINITY;
#pragma unroll
            for (int tc = 0; tc < 4; tc++) {
                float v = acc[tr][tc][rr];
                float vm = (tm != 0.f && imc[tc] != 0.f && v != 0.f) ? v : NEGV;
                vmv[tc] = vm;
                m = fmaxf(m, vm);
            }
            m = fmaxf(m, __shfl_xor(m, 1));
            m = fmaxf(m, __shfl_xor(m, 2));
            m = fmaxf(m, __shfl_xor(m, 4));
            m = fmaxf(m, __shfl_xor(m, 8));
            float ss = 0.f, ws = 0.f;
#pragma unroll
            for (int tc = 0; tc < 4; tc++) {
                float e = __expf(vmv[tc] - m);
                ss += e;
                ws += imc[tc] * e * vmv[tc];
            }
            ss += __shfl_xor(ss, 1); ss += __shfl_xor(ss, 2);
            ss += __shfl_xor(ss, 4); ss += __shfl_xor(ss, 8);
            ws += __shfl_xor(ws, 1); ws += __shfl_xor(ws, 2);
            ws += __shfl_xor(ws, 4); ws += __shfl_xor(ws, 8);
            if (l15 == 0) rowredL[row][wc] = tm * (ws / ss);
            if (wdiag) {
                // W[b=i][l][n] = unmasked softmax over l of att row n
                float inv = 1.f / ss;
                float* Wb = W + (size_t)i * LL * NN;
#pragma unroll
                for (int tc = 0; tc < 4; tc++)
                    Wb[(size_t)(tc * 16 + l15) * NN + row] = __expf(vmv[tc] - m) * inv;
            }
        }
    }

    // ---- col pass 1: per-wr col-max partials over this wave's 64 rows ----
#pragma unroll
    for (int tc = 0; tc < 4; tc++) {
        int col = wc * 64 + tc * 16 + l15;
        float cm = -INFINITY;
#pragma unroll
        for (int tr = 0; tr < 4; tr++)
#pragma unroll
            for (int rr = 0; rr < 4; rr++) {
                float v = acc[tr][tc][rr];
                float vm = (tmr[tr][rr] != 0.f && imc[tc] != 0.f && v != 0.f) ? v : NEGV;
                cm = fmaxf(cm, vm);
            }
        cm = fmaxf(cm, __shfl_xor(cm, 16));
        cm = fmaxf(cm, __shfl_xor(cm, 32));
        if (quad == 0) cpmax[wr][col] = cm;
    }
    __syncthreads();

    // ---- col pass 2: exp/weighted sums with the combined max ----
#pragma unroll
    for (int tc = 0; tc < 4; tc++) {
        int col = wc * 64 + tc * 16 + l15;
        float m2 = fmaxf(cpmax[0][col], cpmax[1][col]);
        float es = 0.f, ws = 0.f;
#pragma unroll
        for (int tr = 0; tr < 4; tr++)
#pragma unroll
            for (int rr = 0; rr < 4; rr++) {
                float v = acc[tr][tc][rr];
                float tm = tmr[tr][rr];
                float vm = (tm != 0.f && imc[tc] != 0.f && v != 0.f) ? v : NEGV;
                float e = __expf(vm - m2);
                es += e;
                ws += tm * e * vm;
            }
        es += __shfl_xor(es, 16); es += __shfl_xor(es, 32);
        ws += __shfl_xor(ws, 16); ws += __shfl_xor(ws, 32);
        if (quad == 0) { cpes[wr][col] = es; cpws[wr][col] = ws; }
    }
    __syncthreads();

    // ---- assembly: wave w (=local j) reduces its S entry ----
    if (wave < 2) {
        int jl = wave;
        float p = rowredL[lane][jl] + rowredL[64 + lane][jl];
        int col = jl * 64 + lane;
        float es = cpes[0][col] + cpes[1][col];
        float ws = cpws[0][col] + cpws[1][col];
        p += imj[col] * (ws / es);
#pragma unroll
        for (int off = 32; off; off >>= 1) p += __shfl_down(p, off);
        if (lane == 0) S[i * BSZ + j0 + jl] = p * (1.f / 128.f);
    }
}

// ---------------------------------------------------------------------------
// Kernel 2: text_emb_i2s[b,n,d] = sum_l W[b][l][n] * img[b][l][d]
// Grid (64 b, 3 d-chunks).  Full W[b] (32 KB) in LDS; img read once.
// Block (0,0) additionally computes the loss from S (fused k_loss).
// ---------------------------------------------------------------------------
__global__ __launch_bounds__(256) void k_i2s(
    const float* __restrict__ W, const float* __restrict__ img,
    const float* __restrict__ S, float* __restrict__ out)
{
    __shared__ float Ws[LL * NN];   // 32 KB, [l][n]
    __shared__ float Ss[BSZ * BSZ]; // 16 KB (loss staging, block (0,0) only)
    const int b = blockIdx.x, tid = threadIdx.x;
    const float* Wb = W + (size_t)b * LL * NN;
#pragma unroll
    for (int q = 0; q < 8; q++) {
        int o = (tid + q * 256) * 4;
        *(float4*)&Ws[o] = *(const float4*)&Wb[o];
    }
    const bool doloss = (blockIdx.x == 0 && blockIdx.y == 0);
    if (doloss) {
#pragma unroll
        for (int q = 0; q < 16; q++) Ss[tid + q * 256] = S[tid + q * 256];
    }
    __syncthreads();

    const int d = blockIdx.y * 256 + tid;
    const float* ib = img + (size_t)b * LL * DD + d;
    float* ob = out + 1 + (size_t)b * NN * DD + d;   // slot 0 = loss

    for (int ng = 0; ng < 8; ng++) {
        float acc[16];
#pragma unroll
        for (int q = 0; q < 16; q++) acc[q] = 0.f;
        for (int l = 0; l < LL; l++) {
            float g = ib[(size_t)l * DD];
            const float* wrow = &Ws[l * NN + ng * 16];
            float4 w0 = *(const float4*)(wrow);
            float4 w1 = *(const float4*)(wrow + 4);
            float4 w2 = *(const float4*)(wrow + 8);
            float4 w3 = *(const float4*)(wrow + 12);
            acc[0]  = fmaf(w0.x, g, acc[0]);  acc[1]  = fmaf(w0.y, g, acc[1]);
            acc[2]  = fmaf(w0.z, g, acc[2]);  acc[3]  = fmaf(w0.w, g, acc[3]);
            acc[4]  = fmaf(w1.x, g, acc[4]);  acc[5]  = fmaf(w1.y, g, acc[5]);
            acc[6]  = fmaf(w1.z, g, acc[6]);  acc[7]  = fmaf(w1.w, g, acc[7]);
            acc[8]  = fmaf(w2.x, g, acc[8]);  acc[9]  = fmaf(w2.y, g, acc[9]);
            acc[10] = fmaf(w2.z, g, acc[10]); acc[11] = fmaf(w2.w, g, acc[11]);
            acc[12] = fmaf(w3.x, g, acc[12]); acc[13] = fmaf(w3.y, g, acc[13]);
            acc[14] = fmaf(w3.z, g, acc[14]); acc[15] = fmaf(w3.w, g, acc[15]);
        }
#pragma unroll
        for (int q = 0; q < 16; q++)
            ob[(size_t)(ng * 16 + q) * DD] = acc[q];
    }

    if (doloss && tid < 64) {
        float diag = Ss[tid * BSZ + tid];
        float m1 = -INFINITY, m2 = -INFINITY;
        for (int jj = 0; jj < BSZ; jj++) {
            m1 = fmaxf(m1, Ss[tid * BSZ + jj]);
            m2 = fmaxf(m2, Ss[jj * BSZ + tid]);
        }
        float s1 = 0.f, s2 = 0.f;
        for (int jj = 0; jj < BSZ; jj++) {
            s1 += __expf(Ss[tid * BSZ + jj] - m1);
            s2 += __expf(Ss[jj * BSZ + tid] - m2);
        }
        float p = 2.f * diag - (m1 + logf(s1)) - (m2 + logf(s2));
#pragma unroll
        for (int off = 32; off; off >>= 1) p += __shfl_down(p, off);
        if (tid == 0) out[0] = -p / (float)BSZ;
    }
}

// ---------------------------------------------------------------------------
extern "C" void kernel_launch(void* const* d_in, const int* in_sizes, int n_in,
                              void* d_out, int out_size, void* d_ws, size_t ws_size,
                              hipStream_t stream)
{
    (void)in_sizes; (void)n_in; (void)out_size; (void)ws_size;
    const float* text = (const float*)d_in[0];   // [64,128,768] fp32
    const float* img  = (const float*)d_in[1];   // [64, 64,768] fp32
    const int*   tm   = (const int*)d_in[2];     // [64,128] int32
    const int*   im   = (const int*)d_in[3];     // [64, 64] int32
    float* out = (float*)d_out;                  // [1 + 64*128*768] fp32

    // workspace layout (bytes); total ~21 MB
    char* ws = (char*)d_ws;
    unsigned short* A = (unsigned short*)(ws);                   // 12.58 MB fp16
    unsigned short* B = (unsigned short*)(ws + 12582912);        //  6.29 MB fp16
    float* S = (float*)(ws + 18874368);                          // 16 KB
    float* W = (float*)(ws + 18890752);                          //  2 MB

    k_prep<<<(TQ + IQ) / 256, 256, 0, stream>>>(
        (const float4*)text, (const float4*)img, (ushort4*)A, (ushort4*)B);

    k_scores<<<2048, 256, 0, stream>>>(A, B, tm, im, S, W);

    dim3 g2(BSZ, 3);
    k_i2s<<<g2, 256, 0, stream>>>(W, img, S, out);
}